// Round 3
// baseline (871.664 us; speedup 1.0000x reference)
//
#include <hip/hip_runtime.h>
#include <math.h>

// Rational-quadratic spline, K=8 bins, tail B=3.
// R3: no max-sub softmax, rcp-based divides, merged log, conditional d0,
//     fused last-block reduction (atomic counter, deterministic order).

#define TAILB 3.0f
#define MINSZ 0.001f

typedef unsigned int u32;

__device__ __forceinline__ void gload_lds16(const void* g, void* l) {
    __builtin_amdgcn_global_load_lds(
        (const __attribute__((address_space(1))) u32*)g,
        (__attribute__((address_space(3))) u32*)l,
        16, 0, 0);
}

__device__ __forceinline__ float frcp(float x) {
    return __builtin_amdgcn_rcpf(x);   // v_rcp_f32, ~1 ulp
}

__device__ __forceinline__ float softplus_d(float u) {
    // softplus(u) + MIN_D
    return fmaxf(u, 0.0f) + __logf(1.0f + __expf(-fabsf(u))) + MINSZ;
}

__launch_bounds__(256, 6)
__global__ void rqs_kernel(const float* __restrict__ x_in,
                           const float* __restrict__ params,
                           float* __restrict__ out,
                           float* __restrict__ partial,
                           u32* counter,            // null -> no fused reduce
                           float* __restrict__ out_sum,
                           int nblocks)
{
    __shared__ __align__(16) float lds[256 * 25];
    __shared__ float wsum[4];
    __shared__ double dsum[4];
    __shared__ int lastflag;

    const int tid = threadIdx.x;
    const int bid = blockIdx.x;
    const int i = bid * 256 + tid;

    const float x = x_in[i];

    // ---- stage 256 rows x 25 floats (25600 B) global->LDS, linear ----
    const float4* src = (const float4*)params + (size_t)bid * 1600;
    float4* dst = (float4*)lds;
    #pragma unroll
    for (int v = 0; v < 6; ++v) {
        const int q = tid + v * 256;
        gload_lds16(src + q, dst + q);
    }
    if (tid < 64) {
        const int q = tid + 1536;
        gload_lds16(src + q, dst + q);
    }

    const float xi = fminf(fmaxf(x, -TAILB), TAILB);
    __syncthreads();

    const float* row = &lds[tid * 25];
    const float fac_num = (2.0f * TAILB) * (2.0f * TAILB - 8.0f * MINSZ); // 35.952

    // ---- widths: softmax (no max-sub; |u|<~6 is safe) ----
    float ew[8];
    float s = 0.0f;
    #pragma unroll
    for (int j = 0; j < 8; ++j) { ew[j] = __expf(row[j]); s += ew[j]; }
    const float facw = fac_num * frcp(s);

    // fused cumsum + count + knot select (inner knots are monotone)
    float c = 0.0f;
    int idx = 0;
    float cw_k = -TAILB, cw_k1 = TAILB;
    bool found = false;
    #pragma unroll
    for (int j = 0; j < 7; ++j) {
        c = fmaf(ew[j], facw, c + MINSZ);
        const bool ge = (xi >= c);
        idx += ge ? 1 : 0;
        cw_k  = ge ? c : cw_k;
        cw_k1 = (!ge && !found) ? c : cw_k1;
        found = found || !ge;
    }

    // ---- heights: softmax + select by idx ----
    float ch_k = -TAILB, ch_k1 = TAILB;
    {
        float eh[8];
        float sh = 0.0f;
        #pragma unroll
        for (int j = 0; j < 8; ++j) { eh[j] = __expf(row[8 + j]); sh += eh[j]; }
        const float fach = fac_num * frcp(sh);
        c = 0.0f;
        #pragma unroll
        for (int j = 1; j <= 7; ++j) {
            c = fmaf(eh[j - 1], fach, c + MINSZ);
            ch_k  = (idx == j)     ? c : ch_k;
            ch_k1 = (idx + 1 == j) ? c : ch_k1;
        }
    }

    // ---- derivatives: exactly the 2 needed (idx==0 makes d_k == d0) ----
    const float d_k  = softplus_d(row[16 + idx]);
    const float d_k1 = softplus_d(row[17 + idx]);

    // ---- rational-quadratic transform ----
    const float bw  = cw_k1 - cw_k;
    const float bh  = ch_k1 - ch_k;
    const float rbw = frcp(bw);
    const float th  = (xi - cw_k) * rbw;
    const float omt = 1.0f - th;
    const float th2 = th * th;
    const float t1m = th * omt;
    const float num = bh * fmaf(d_k, th2, d_k1 * t1m);
    const float den = fmaf(2.0f * d_k1, t1m, fmaf(d_k, th2, omt * omt));
    const float out_in = fmaf(num, frcp(den), ch_k);

    const bool inside = (x >= -TAILB) && (x <= TAILB);
    out[i] = inside ? out_in : x;

    // log(dk1*dk*bh*den^2 / (bw*den^2)) == log(dk1*dk*bh/bw); merge with
    // the outside branch's log(d0) into ONE v_log_f32.
    float ldarg = d_k1 * d_k * bh * rbw;
    if (!__all(inside)) {                 // only waves containing a tail lane
        const float d0 = softplus_d(row[16]);
        ldarg = inside ? ldarg : d0;
    }
    const float ldv = __logf(ldarg);

    // ---- block reduction (float tree; error << threshold) ----
    float acc = ldv;
    #pragma unroll
    for (int off = 32; off > 0; off >>= 1)
        acc += __shfl_down(acc, off);
    const int wave = tid >> 6, lane = tid & 63;
    if (lane == 0) wsum[wave] = acc;
    __syncthreads();

    if (counter == nullptr) {
        if (tid == 0)
            partial[bid] = (wsum[0] + wsum[1]) + (wsum[2] + wsum[3]);
        return;
    }

    // ---- fused final reduction: last block to finish sums partials ----
    if (tid == 0) {
        const float p = (wsum[0] + wsum[1]) + (wsum[2] + wsum[3]);
        __hip_atomic_store(&partial[bid], p, __ATOMIC_RELAXED,
                           __HIP_MEMORY_SCOPE_AGENT);
        const u32 old = __hip_atomic_fetch_add(counter, 1u, __ATOMIC_ACQ_REL,
                                               __HIP_MEMORY_SCOPE_AGENT);
        lastflag = (old == (u32)(nblocks - 1)) ? 1 : 0;
    }
    __syncthreads();

    if (lastflag) {
        // deterministic: order depends only on indices, not on which block
        double dacc = 0.0;
        for (int q = tid; q < nblocks; q += 256)
            dacc += (double)__hip_atomic_load(&partial[q], __ATOMIC_RELAXED,
                                              __HIP_MEMORY_SCOPE_AGENT);
        #pragma unroll
        for (int off = 32; off > 0; off >>= 1)
            dacc += __shfl_down(dacc, off);
        if (lane == 0) dsum[wave] = dacc;
        __syncthreads();
        if (tid == 0)
            *out_sum = (float)((dsum[0] + dsum[1]) + (dsum[2] + dsum[3]));
    }
}

__global__ void rqs_reduce(const float* __restrict__ partial, int nb,
                           float* __restrict__ out_sum)
{
    const int tid = threadIdx.x;              // 1024 threads
    const int nb4 = nb >> 2;
    const float4* p4 = (const float4*)partial;
    double acc = 0.0;
    for (int q = tid; q < nb4; q += 1024) {
        float4 v = p4[q];
        acc += (double)v.x + (double)v.y + (double)v.z + (double)v.w;
    }
    #pragma unroll
    for (int off = 32; off > 0; off >>= 1)
        acc += __shfl_down(acc, off);
    __shared__ double wsum[16];
    const int wave = tid >> 6, lane = tid & 63;
    if (lane == 0) wsum[wave] = acc;
    __syncthreads();
    if (tid == 0) {
        double t = 0.0;
        #pragma unroll
        for (int w = 0; w < 16; ++w) t += wsum[w];
        *out_sum = (float)t;
    }
}

extern "C" void kernel_launch(void* const* d_in, const int* in_sizes, int n_in,
                              void* d_out, int out_size, void* d_ws, size_t ws_size,
                              hipStream_t stream) {
    const float* x      = (const float*)d_in[0];
    const float* params = (const float*)d_in[1];
    float* out = (float*)d_out;
    const int n = in_sizes[0];          // 4194304, divisible by 256
    const int nb = n / 256;             // 16384 blocks
    float* partial = (float*)d_ws;

    const size_t need = (size_t)nb * 4 + 4;
    if (ws_size >= need) {
        u32* counter = (u32*)((char*)d_ws + (size_t)nb * 4);
        hipMemsetAsync(counter, 0, 4, stream);   // capturable memset node
        hipLaunchKernelGGL(rqs_kernel, dim3(nb), dim3(256), 0, stream,
                           x, params, out, partial, counter, out + n, nb);
    } else {
        hipLaunchKernelGGL(rqs_kernel, dim3(nb), dim3(256), 0, stream,
                           x, params, out, partial, (u32*)nullptr, out + n, nb);
        hipLaunchKernelGGL(rqs_reduce, dim3(1), dim3(1024), 0, stream,
                           partial, nb, out + n);
    }
}

// Round 4
// 87.292 us; speedup vs baseline: 9.9857x; 9.9857x over previous
//
#include <hip/hip_runtime.h>
#include <math.h>

// Rational-quadratic spline, K=8 bins, tail B=3.
// R4: R2's two-kernel structure + R3's VALU cuts (no max-sub softmax,
//     rcp divides, merged single log, only 2 softplus, float wave-reduce).
//     The R3 fused single-counter reduction is REMOVED (16k serialized
//     agent-scope RMWs on one dword cost ~800us -- Guideline 12).

#define TAILB 3.0f
#define MINSZ 0.001f

typedef unsigned int u32;

__device__ __forceinline__ void gload_lds16(const void* g, void* l) {
    __builtin_amdgcn_global_load_lds(
        (const __attribute__((address_space(1))) u32*)g,
        (__attribute__((address_space(3))) u32*)l,
        16, 0, 0);
}

__device__ __forceinline__ float frcp(float x) {
    return __builtin_amdgcn_rcpf(x);   // v_rcp_f32, ~1 ulp
}

__device__ __forceinline__ float softplus_d(float u) {
    // softplus(u) + MIN_D
    return fmaxf(u, 0.0f) + __logf(1.0f + __expf(-fabsf(u))) + MINSZ;
}

__launch_bounds__(256, 6)
__global__ void rqs_kernel(const float* __restrict__ x_in,
                           const float* __restrict__ params,
                           float* __restrict__ out,
                           float* __restrict__ partial)
{
    __shared__ __align__(16) float lds[256 * 25];
    __shared__ float wsum[4];

    const int tid = threadIdx.x;
    const int bid = blockIdx.x;
    const int i = bid * 256 + tid;

    const float x = x_in[i];

    // ---- stage 256 rows x 25 floats (25600 B) global->LDS, linear ----
    const float4* src = (const float4*)params + (size_t)bid * 1600;
    float4* dst = (float4*)lds;
    #pragma unroll
    for (int v = 0; v < 6; ++v) {
        const int q = tid + v * 256;
        gload_lds16(src + q, dst + q);
    }
    if (tid < 64) {
        const int q = tid + 1536;
        gload_lds16(src + q, dst + q);
    }

    const float xi = fminf(fmaxf(x, -TAILB), TAILB);
    __syncthreads();

    const float* row = &lds[tid * 25];
    const float fac_num = (2.0f * TAILB) * (2.0f * TAILB - 8.0f * MINSZ); // 35.952

    // ---- widths: softmax (no max-sub; |u| small enough for fp32 exp) ----
    float ew[8];
    float s = 0.0f;
    #pragma unroll
    for (int j = 0; j < 8; ++j) { ew[j] = __expf(row[j]); s += ew[j]; }
    const float facw = fac_num * frcp(s);

    // fused cumsum + count + knot select (inner knots are monotone)
    float c = 0.0f;
    int idx = 0;
    float cw_k = -TAILB, cw_k1 = TAILB;
    bool found = false;
    #pragma unroll
    for (int j = 0; j < 7; ++j) {
        c = fmaf(ew[j], facw, c + MINSZ);
        const bool ge = (xi >= c);
        idx += ge ? 1 : 0;
        cw_k  = ge ? c : cw_k;
        cw_k1 = (!ge && !found) ? c : cw_k1;
        found = found || !ge;
    }

    // ---- heights: softmax + select by idx ----
    float ch_k = -TAILB, ch_k1 = TAILB;
    {
        float eh[8];
        float sh = 0.0f;
        #pragma unroll
        for (int j = 0; j < 8; ++j) { eh[j] = __expf(row[8 + j]); sh += eh[j]; }
        const float fach = fac_num * frcp(sh);
        c = 0.0f;
        #pragma unroll
        for (int j = 1; j <= 7; ++j) {
            c = fmaf(eh[j - 1], fach, c + MINSZ);
            ch_k  = (idx == j)     ? c : ch_k;
            ch_k1 = (idx + 1 == j) ? c : ch_k1;
        }
    }

    // ---- derivatives: exactly the 2 needed (idx==0 makes d_k == d0) ----
    const float d_k  = softplus_d(row[16 + idx]);
    const float d_k1 = softplus_d(row[17 + idx]);

    // ---- rational-quadratic transform ----
    const float bw  = cw_k1 - cw_k;
    const float bh  = ch_k1 - ch_k;
    const float rbw = frcp(bw);
    const float th  = (xi - cw_k) * rbw;
    const float omt = 1.0f - th;
    const float th2 = th * th;
    const float t1m = th * omt;
    const float num = bh * fmaf(d_k, th2, d_k1 * t1m);
    const float den = fmaf(2.0f * d_k1, t1m, fmaf(d_k, th2, omt * omt));
    const float out_in = fmaf(num, frcp(den), ch_k);

    const bool inside = (x >= -TAILB) && (x <= TAILB);
    out[i] = inside ? out_in : x;

    // log(dk1*dk*bh*den^2 / (bw*den^2)) == log(dk1*dk*bh/bw); merge with
    // the outside branch's log(d0) into ONE v_log_f32.
    float ldarg = d_k1 * d_k * bh * rbw;
    if (!__all(inside)) {                 // only waves containing a tail lane
        const float d0 = softplus_d(row[16]);
        ldarg = inside ? ldarg : d0;
    }
    const float ldv = __logf(ldarg);

    // ---- block reduction (float tree; error << threshold) ----
    float acc = ldv;
    #pragma unroll
    for (int off = 32; off > 0; off >>= 1)
        acc += __shfl_down(acc, off);
    const int wave = tid >> 6, lane = tid & 63;
    if (lane == 0) wsum[wave] = acc;
    __syncthreads();
    if (tid == 0)
        partial[bid] = (wsum[0] + wsum[1]) + (wsum[2] + wsum[3]);
}

__global__ void rqs_reduce(const float* __restrict__ partial, int nb,
                           float* __restrict__ out_sum)
{
    const int tid = threadIdx.x;              // 1024 threads
    const int nb4 = nb >> 2;                  // nb divisible by 4
    const float4* p4 = (const float4*)partial;
    double acc = 0.0;
    for (int q = tid; q < nb4; q += 1024) {
        float4 v = p4[q];
        acc += (double)v.x + (double)v.y + (double)v.z + (double)v.w;
    }
    #pragma unroll
    for (int off = 32; off > 0; off >>= 1)
        acc += __shfl_down(acc, off);
    __shared__ double wsum[16];
    const int wave = tid >> 6, lane = tid & 63;
    if (lane == 0) wsum[wave] = acc;
    __syncthreads();
    if (tid == 0) {
        double t = 0.0;
        #pragma unroll
        for (int w = 0; w < 16; ++w) t += wsum[w];
        *out_sum = (float)t;
    }
}

extern "C" void kernel_launch(void* const* d_in, const int* in_sizes, int n_in,
                              void* d_out, int out_size, void* d_ws, size_t ws_size,
                              hipStream_t stream) {
    const float* x      = (const float*)d_in[0];
    const float* params = (const float*)d_in[1];
    float* out = (float*)d_out;
    const int n = in_sizes[0];          // 4194304, divisible by 256
    const int nb = n / 256;             // 16384 blocks
    float* partial = (float*)d_ws;      // nb*4 = 64 KB scratch

    hipLaunchKernelGGL(rqs_kernel, dim3(nb), dim3(256), 0, stream,
                       x, params, out, partial);
    hipLaunchKernelGGL(rqs_reduce, dim3(1), dim3(1024), 0, stream,
                       partial, nb, out + n);
}